// Round 9
// baseline (66.597 us; speedup 1.0000x reference)
//
#include <hip/hip_runtime.h>
#include <hip/hip_bf16.h>

#define BHN 32      // B*H
#define SEQ 4096
#define DIM 128
#define CHUNKS 8
#define SROWS (SEQ / CHUNKS)   // 512 rows per phase-1 block
#define TROWS 64               // rows per LDS tile
#define NTILE (SROWS / TROWS)  // 8 tiles per block

typedef __bf16 bf16x8 __attribute__((ext_vector_type(8)));
typedef __bf16 bf16x4 __attribute__((ext_vector_type(4)));
typedef float  f32x4  __attribute__((ext_vector_type(4)));

__device__ __forceinline__ bf16x8 cvt8(const float* f) {
    bf16x8 r;
#pragma unroll
    for (int i = 0; i < 8; ++i) r[i] = (__bf16)f[i];
    return r;
}

// ---------------------------------------------------------------------------
// Phase 1 (8-wave, DEPTH-2 PIPELINE): partial kv^T. C[e][d]=sum_s v[s][e]*k[s][d]
// grid = 32 heads * 8 chunks = 256 blocks (1 block/CU).
//
// R8 confirmed: CHUNKS=8 traffic diet -> 66.1us (best). p1 is the only
// sub-ceiling component left (~142MB / ~30us real = 4.7 TB/s vs 6.3 copy
// ceiling; p2 is AT ceiling, reduce+boundaries ~5-6us).
//
// R9: prefetch depth 1 -> 2. MLP arithmetic: depth-1 = 128B/thread in
// flight, marginal at ~900ns HBM latency for the per-CU BW share; depth-2
// doubles it (256B/thread, 128KB/CU). KEY: at 1 block/CU there are only
// 2 waves/SIMD, so VGPR<=256 is FREE -- the register pressure that killed
// R1/R2/R4 experiments is no longer a constraint. kr/vr[2][4] ping-pong
// (tile t in slot t&1, static index after full unroll); pack(t) empties
// the slot, prefetch(t+2) refills it; compiler emits counted vmcnt(8) so
// tile t+1's loads stay in flight across the barrier and MFMA.
//
// Session ledger: occupancy levers dead (32/44/66% all neutral); clamp
// spilled; interleaved map -14%; agent-atomic fusion -58%; coop fusion
// rejected on re-gridding arithmetic (phase B would run at 8 waves/CU).
//
// LDS 64 KB dbuf; lgkmcnt-only barrier (no vmcnt drain) as in R5/R8.
// LDS swizzle: elem (d,s) at d*64 + (((s>>3) ^ key(d))*8) + (s&7),
//   key(d) = (d&7) ^ ((d>>2)&7)  -> <=2-way on both write and read lanes.
// ---------------------------------------------------------------------------
__global__ __launch_bounds__(512) void p1_kv(const float* __restrict__ kin,
                                             const float* __restrict__ vin,
                                             __bf16* __restrict__ ws1) {
    __shared__ __align__(16) __bf16 kt[2][DIM][TROWS];  // 32 KB
    __shared__ __align__(16) __bf16 vt[2][DIM][TROWS];  // 32 KB

    const int bh    = blockIdx.x >> 3;
    const int chunk = blockIdx.x & 7;
    const int tid = threadIdx.x;

    const int dcol = tid & 31;     // d-quad index 0..31  -> d0 = dcol*4
    const int sgrp = tid >> 5;     // s-quad index 0..15  -> s0 = sgrp*4
    const int d0 = dcol * 4;
    const int s0 = sgrp * 4;

    const int w = tid >> 6;
    const int l = tid & 63;
    const int g = l >> 4;
    const int c = l & 15;

    const float* kb = kin + (size_t)bh * SEQ * DIM + (size_t)chunk * SROWS * DIM;
    const float* vb = vin + (size_t)bh * SEQ * DIM + (size_t)chunk * SROWS * DIM;

    f32x4 acc[8];
#pragma unroll
    for (int nt = 0; nt < 8; ++nt) acc[nt] = (f32x4){0.f, 0.f, 0.f, 0.f};

    // depth-2 staging: tile t lives in slot t&1; statically indexed
    f32x4 kr[2][4], vr[2][4];
    {   // prologue: tiles 0 and 1
        const size_t off0 = (size_t)s0 * DIM + d0;
        const size_t off1 = ((size_t)(TROWS + s0)) * DIM + d0;
#pragma unroll
        for (int j = 0; j < 4; ++j) {
            kr[0][j] = *(const f32x4*)(kb + off0 + j * DIM);
            vr[0][j] = *(const f32x4*)(vb + off0 + j * DIM);
        }
#pragma unroll
        for (int j = 0; j < 4; ++j) {
            kr[1][j] = *(const f32x4*)(kb + off1 + j * DIM);
            vr[1][j] = *(const f32x4*)(vb + off1 + j * DIM);
        }
    }

#pragma unroll
    for (int t = 0; t < NTILE; ++t) {
        const int p = t & 1;   // compile-time after full unroll

        // ---- pack tile t (compiler waits counted vmcnt for ITS 8 loads;
        //      tile t+1's 8 loads remain outstanding)
#pragma unroll
        for (int jd = 0; jd < 4; ++jd) {
            const int dd  = d0 + jd;
            const int key = (dd & 7) ^ ((dd >> 2) & 7);
            const int o   = (((sgrp >> 1) ^ key) * 8) + (sgrp & 1) * 4;
            bf16x4 pk, pv;
#pragma unroll
            for (int j = 0; j < 4; ++j) {
                pk[j] = (__bf16)kr[p][j][jd];
                pv[j] = (__bf16)vr[p][j][jd];
            }
            *(bf16x4*)&kt[p][dd][o] = pk;
            *(bf16x4*)&vt[p][dd][o] = pv;
        }

        // ---- prefetch tile t+2 into the just-freed slot; fences pin it
        // (R3 lesson: unfenced prefetch is silently sunk to its consumer)
        __builtin_amdgcn_sched_barrier(0);
        if (t + 2 < NTILE) {
            const size_t off = ((size_t)((t + 2) * TROWS + s0)) * DIM + d0;
#pragma unroll
            for (int j = 0; j < 4; ++j) {
                kr[p][j] = *(const f32x4*)(kb + off + j * DIM);
                vr[p][j] = *(const f32x4*)(vb + off + j * DIM);
            }
        }
        __builtin_amdgcn_sched_barrier(0);

        // ---- producer handoff WITHOUT vmcnt drain: my ds_writes done, then
        //      block-wide barrier. Up to 16 loads stay in flight across MFMA.
        asm volatile("s_waitcnt lgkmcnt(0)" ::: "memory");
        __builtin_amdgcn_s_barrier();

        // ---- MFMA: wave w owns e-strip [w*16,+16); K-dim 64 s (2 steps)
        const int e    = w * 16 + c;
        const int keyE = (e & 7) ^ ((e >> 2) & 7);
#pragma unroll
        for (int st = 0; st < 2; ++st) {
            bf16x8 af = *(const bf16x8*)&vt[p][e][((st * 4 + g) ^ keyE) * 8];
#pragma unroll
            for (int nt = 0; nt < 8; ++nt) {
                const int d    = nt * 16 + c;
                const int keyD = (d & 7) ^ ((d >> 2) & 7);
                bf16x8 bfr = *(const bf16x8*)&kt[p][d][((st * 4 + g) ^ keyD) * 8];
                acc[nt] = __builtin_amdgcn_mfma_f32_16x16x32_bf16(af, bfr, acc[nt], 0, 0, 0);
            }
        }
        // no trailing barrier: next pack writes buffer p^1. A wave reaches
        // pack of buffer p again only after the NEXT barrier, by which time
        // every wave has retired its MFMA(t) LDS reads (program order:
        // MFMA(t) -> pack(t+1) -> barrier(t+1)). Verified R5/R6/R8.
    }

    // store bf16 partials, MFMA-native flat layout: f = nt*2048 + tid*4 + r
    // (each bf16x4 store instr = 512B/wave contiguous burst)
    __bf16* outp = ws1 + ((size_t)chunk * BHN + bh) * (DIM * DIM);
#pragma unroll
    for (int nt = 0; nt < 8; ++nt) {
        bf16x4 pq;
#pragma unroll
        for (int r = 0; r < 4; ++r) pq[r] = (__bf16)acc[nt][r];
        *(bf16x4*)(outp + nt * 2048 + tid * 4) = pq;
    }
}

// ---------------------------------------------------------------------------
// Phase 1.5: reduce 8 bf16 partials (fp32 accum) -> bf16 kv^T swizzled for p2:
//   element (e,d) at  e*128 + ((d>>3)^(e&15))*8 + (d&7)
// Decode of p1's flat layout  f = nt*2048 + tid*4 + r, tid = w*64+g*16+c:
//   nt=f>>11; w=(f>>8)&7; g=(f>>6)&3; c=(f>>2)&15; r=f&3
//   e = w*16 + g*4 + r ;  d = nt*16 + c
// 256 blocks * 256 threads; thread owns 8 consecutive f (16B loads/chunk).
// ---------------------------------------------------------------------------
__global__ __launch_bounds__(256) void p1_reduce(const __bf16* __restrict__ ws1,
                                                 __bf16* __restrict__ ws2) {
    const int t   = blockIdx.x * 256 + threadIdx.x;  // 65536 threads
    const int bh  = t >> 11;
    const int r11 = t & 2047;

    const __bf16* base = ws1 + (size_t)bh * (DIM * DIM) + r11 * 8;
    float s[8] = {0.f, 0.f, 0.f, 0.f, 0.f, 0.f, 0.f, 0.f};
#pragma unroll
    for (int ch = 0; ch < CHUNKS; ++ch) {
        bf16x8 a = *(const bf16x8*)(base + (size_t)ch * BHN * DIM * DIM);
#pragma unroll
        for (int i = 0; i < 8; ++i) s[i] += (float)a[i];
    }

    __bf16* dst = ws2 + (size_t)bh * (DIM * DIM);
#pragma unroll
    for (int i = 0; i < 8; ++i) {
        const int f  = r11 * 8 + i;
        const int nt = f >> 11;
        const int wv = (f >> 8) & 7;
        const int gg = (f >> 6) & 3;
        const int cc = (f >> 2) & 15;
        const int r  = f & 3;
        const int e  = wv * 16 + gg * 4 + r;
        const int d  = nt * 16 + cc;
        dst[e * DIM + (((d >> 3) ^ (e & 15)) * 8) + (d & 7)] = (__bf16)s[i];
    }
}

// ---------------------------------------------------------------------------
// Phase 2 (flipped operands): out[s][e] = v[s][e] + sum_d q[s][d] * kv[d][e]
// Compute C[e][s] = mfma(A = kv_frag (M=e), B = q_frag (N=s)).
// Each lane holds 4 CONSECUTIVE e per fragment -> f32x4 epilogue.
// grid = 32 heads * 32 row-chunks = 1024 blocks, 512 threads (8 waves).
// UNCHANGED all session: at/above copy ceiling (~193MB / ~30us real,
// v served from L3) -- this is why fusion with p1's grid was rejected.
// ---------------------------------------------------------------------------
__global__ __launch_bounds__(512) void p2_qkv(const float* __restrict__ qin,
                                              const float* __restrict__ vin,
                                              const __bf16* __restrict__ ws2,
                                              float* __restrict__ outp) {
    __shared__ __align__(16) __bf16 kvs[DIM * DIM];

    const int bh = blockIdx.x & 31;
    const int rc = blockIdx.x >> 5;
    const int tid = threadIdx.x;

    {   // linear 16B-copy of the (already swizzled) 32 KB head slab into LDS
        const uint4* src = (const uint4*)(ws2 + (size_t)bh * DIM * DIM);
        uint4* dst = (uint4*)kvs;
#pragma unroll
        for (int j = 0; j < 4; ++j) dst[tid + j * 512] = src[tid + j * 512];
    }
    __syncthreads();

    const int w = tid >> 6;
    const int l = tid & 63;
    const int g = l >> 4;
    const int c = l & 15;
    const int s = rc * 128 + w * 16 + c;     // this lane's output row

    // hoist all 4 Q fragments: B[d][s], lane holds q[s][ks*32 + g*8 .. +8)
    const float* qrow = qin + (size_t)bh * SEQ * DIM + (size_t)s * DIM + g * 8;
    bf16x8 bq[4];
#pragma unroll
    for (int ks = 0; ks < 4; ++ks) {
        f32x4 x = *(const f32x4*)(qrow + ks * 32);
        f32x4 y = *(const f32x4*)(qrow + ks * 32 + 4);
        float tmp[8];
        tmp[0]=x[0]; tmp[1]=x[1]; tmp[2]=x[2]; tmp[3]=x[3];
        tmp[4]=y[0]; tmp[5]=y[1]; tmp[6]=y[2]; tmp[7]=y[3];
        bq[ks] = cvt8(tmp);
    }

    f32x4 acc[8];
#pragma unroll
    for (int et = 0; et < 8; ++et) acc[et] = (f32x4){0.f, 0.f, 0.f, 0.f};

#pragma unroll
    for (int ks = 0; ks < 4; ++ks) {
#pragma unroll
        for (int et = 0; et < 8; ++et) {
            const int e = et * 16 + c;                 // A's M index = lane&15
            const int slot = (ks * 4 + g) ^ c;         // unswizzle: d-slice = ks*32+g*8
            bf16x8 a = *(const bf16x8*)&kvs[e * DIM + slot * 8];
            acc[et] = __builtin_amdgcn_mfma_f32_16x16x32_bf16(a, bq[ks], acc[et], 0, 0, 0);
        }
    }

    // epilogue: lane holds out[s][et*16 + g*4 .. +4) -> vectorized V add + store
    const float* vb = vin + (size_t)bh * SEQ * DIM;
    float* ob = outp + (size_t)bh * SEQ * DIM;
#pragma unroll
    for (int et = 0; et < 8; ++et) {
        const size_t idx = (size_t)s * DIM + et * 16 + g * 4;
        f32x4 vv = *(const f32x4*)(vb + idx);
        f32x4 o = acc[et] + vv;
        *(f32x4*)(ob + idx) = o;
    }
}

// ---------------------------------------------------------------------------
// Workspace: ws1 (8 x 1 MiB bf16 partials) + ws2 (1 MiB reduced kv) = 9 MiB.
// ---------------------------------------------------------------------------
extern "C" void kernel_launch(void* const* d_in, const int* in_sizes, int n_in,
                              void* d_out, int out_size, void* d_ws, size_t ws_size,
                              hipStream_t stream) {
    const float* q = (const float*)d_in[0];
    const float* k = (const float*)d_in[1];
    const float* v = (const float*)d_in[2];
    float* out = (float*)d_out;

    __bf16* ws1 = (__bf16*)d_ws;                                   // 8 MiB partials
    __bf16* ws2 = (__bf16*)((char*)d_ws + (size_t)CHUNKS * BHN * DIM * DIM * 2);

    p1_kv<<<BHN * CHUNKS, 512, 0, stream>>>(k, v, ws1);
    p1_reduce<<<(BHN * DIM * DIM / 8) / 256, 256, 0, stream>>>(ws1, ws2);
    p2_qkv<<<BHN * (SEQ / 128), 512, 0, stream>>>(q, v, ws2, out);
}

// Round 10
// 65.817 us; speedup vs baseline: 1.0119x; 1.0119x over previous
//
#include <hip/hip_runtime.h>
#include <hip/hip_bf16.h>

#define BHN 32      // B*H
#define SEQ 4096
#define DIM 128
#define CHUNKS 8
#define SROWS (SEQ / CHUNKS)   // 512 rows per phase-1 block
#define TROWS 64               // rows per LDS tile
#define NTILE (SROWS / TROWS)  // 8 tiles per block

typedef __bf16 bf16x8 __attribute__((ext_vector_type(8)));
typedef __bf16 bf16x4 __attribute__((ext_vector_type(4)));
typedef float  f32x4  __attribute__((ext_vector_type(4)));

__device__ __forceinline__ bf16x8 cvt8(const float* f) {
    bf16x8 r;
#pragma unroll
    for (int i = 0; i < 8; ++i) r[i] = (__bf16)f[i];
    return r;
}

// ---------------------------------------------------------------------------
// Phase 1 (8-wave, depth-1 pipeline): partial kv^T. C[e][d]=sum_s v[s][e]*k[s][d]
// grid = 32 heads * 8 chunks = 256 blocks (1 block/CU). BEST MEASURED: 66.1us.
//
// SESSION LEDGER (R0-R9), all falsified by measurement:
//   - occupancy 17/32/44/66%: p1 dur invariant -> occupancy lever dead.
//   - __launch_bounds__(512,8) reg clamp: spilled, +60MB scratch, +18us.
//   - interleaved chunk->tile map: -14% (L2-fill amplification).
//   - split-K tail fusion w/ agent atomics: -58% (L2 wb/inv storms).
//   - prefetch depth 2 (R9): neutral -> p1 is service-rate-bound, not
//     MLP-starved. Depth-1 retained (load-bearing at 1 block/CU).
//   - CHUNKS 16->8 traffic diet (R8): -1.8us, exactly predicted bytes. WIN.
// Floor arithmetic: 352MB mandatory traffic / 6.3 TB/s = ~56us; at 66.1 we
// run 85% of floor; residual = 2 dispatch boundaries + p1's transpose-
// consume access mix. Scheduling levers exhausted -> roofline next round.
//
// LDS 64 KB dbuf; lgkmcnt-only barrier (no vmcnt drain); reg prefetch
// pinned by sched_barrier(0) fences (unfenced = silently sunk, R3).
// LDS swizzle: elem (d,s) at d*64 + (((s>>3) ^ key(d))*8) + (s&7),
//   key(d) = (d&7) ^ ((d>>2)&7)  -> <=2-way on both write and read lanes.
// ---------------------------------------------------------------------------
__global__ __launch_bounds__(512) void p1_kv(const float* __restrict__ kin,
                                             const float* __restrict__ vin,
                                             __bf16* __restrict__ ws1) {
    __shared__ __align__(16) __bf16 kt[2][DIM][TROWS];  // 32 KB
    __shared__ __align__(16) __bf16 vt[2][DIM][TROWS];  // 32 KB

    const int bh    = blockIdx.x >> 3;
    const int chunk = blockIdx.x & 7;
    const int tid = threadIdx.x;

    const int dcol = tid & 31;     // d-quad index 0..31  -> d0 = dcol*4
    const int sgrp = tid >> 5;     // s-quad index 0..15  -> s0 = sgrp*4
    const int d0 = dcol * 4;
    const int s0 = sgrp * 4;

    const int w = tid >> 6;
    const int l = tid & 63;
    const int g = l >> 4;
    const int c = l & 15;

    const float* kb = kin + (size_t)bh * SEQ * DIM + (size_t)chunk * SROWS * DIM;
    const float* vb = vin + (size_t)bh * SEQ * DIM + (size_t)chunk * SROWS * DIM;

    f32x4 acc[8];
#pragma unroll
    for (int nt = 0; nt < 8; ++nt) acc[nt] = (f32x4){0.f, 0.f, 0.f, 0.f};

    // single set of staging regs; refilled for t+1 right after pack(t)
    f32x4 kr[4], vr[4];
    {   // prologue: tile 0
        const size_t off = (size_t)s0 * DIM + d0;
#pragma unroll
        for (int j = 0; j < 4; ++j) {
            kr[j] = *(const f32x4*)(kb + off + j * DIM);
            vr[j] = *(const f32x4*)(vb + off + j * DIM);
        }
    }

#pragma unroll
    for (int t = 0; t < NTILE; ++t) {
        const int p = t & 1;   // compile-time after full unroll

        // ---- pack current tile (compiler waits vmcnt for its loads)
#pragma unroll
        for (int jd = 0; jd < 4; ++jd) {
            const int dd  = d0 + jd;
            const int key = (dd & 7) ^ ((dd >> 2) & 7);
            const int o   = (((sgrp >> 1) ^ key) * 8) + (sgrp & 1) * 4;
            bf16x4 pk, pv;
#pragma unroll
            for (int j = 0; j < 4; ++j) {
                pk[j] = (__bf16)kr[j][jd];
                pv[j] = (__bf16)vr[j][jd];
            }
            *(bf16x4*)&kt[p][dd][o] = pk;
            *(bf16x4*)&vt[p][dd][o] = pv;
        }

        // ---- prefetch tile t+1 into the just-freed regs; fences pin it here
        __builtin_amdgcn_sched_barrier(0);
        if (t + 1 < NTILE) {
            const size_t off = ((size_t)((t + 1) * TROWS + s0)) * DIM + d0;
#pragma unroll
            for (int j = 0; j < 4; ++j) {
                kr[j] = *(const f32x4*)(kb + off + j * DIM);
                vr[j] = *(const f32x4*)(vb + off + j * DIM);
            }
        }
        __builtin_amdgcn_sched_barrier(0);

        // ---- producer handoff WITHOUT vmcnt drain: my ds_writes done, then
        //      block-wide barrier. Prefetch loads stay in flight across MFMA.
        asm volatile("s_waitcnt lgkmcnt(0)" ::: "memory");
        __builtin_amdgcn_s_barrier();

        // ---- MFMA: wave w owns e-strip [w*16,+16); K-dim 64 s (2 steps)
        const int e    = w * 16 + c;
        const int keyE = (e & 7) ^ ((e >> 2) & 7);
#pragma unroll
        for (int st = 0; st < 2; ++st) {
            bf16x8 af = *(const bf16x8*)&vt[p][e][((st * 4 + g) ^ keyE) * 8];
#pragma unroll
            for (int nt = 0; nt < 8; ++nt) {
                const int d    = nt * 16 + c;
                const int keyD = (d & 7) ^ ((d >> 2) & 7);
                bf16x8 bfr = *(const bf16x8*)&kt[p][d][((st * 4 + g) ^ keyD) * 8];
                acc[nt] = __builtin_amdgcn_mfma_f32_16x16x32_bf16(af, bfr, acc[nt], 0, 0, 0);
            }
        }
        // no trailing barrier: next pack writes buffer p^1. A wave reaches
        // pack of buffer p again only after the NEXT barrier, by which time
        // every wave has retired its MFMA(t) LDS reads. Verified R5/R8.
    }

    // store bf16 partials, MFMA-native flat layout: f = nt*2048 + tid*4 + r
    // (each bf16x4 store instr = 512B/wave contiguous burst)
    __bf16* outp = ws1 + ((size_t)chunk * BHN + bh) * (DIM * DIM);
#pragma unroll
    for (int nt = 0; nt < 8; ++nt) {
        bf16x4 pq;
#pragma unroll
        for (int r = 0; r < 4; ++r) pq[r] = (__bf16)acc[nt][r];
        *(bf16x4*)(outp + nt * 2048 + tid * 4) = pq;
    }
}

// ---------------------------------------------------------------------------
// Phase 1.5: reduce 8 bf16 partials (fp32 accum) -> bf16 kv^T swizzled for p2:
//   element (e,d) at  e*128 + ((d>>3)^(e&15))*8 + (d&7)
// Decode of p1's flat layout  f = nt*2048 + tid*4 + r, tid = w*64+g*16+c:
//   nt=f>>11; w=(f>>8)&7; g=(f>>6)&3; c=(f>>2)&15; r=f&3
//   e = w*16 + g*4 + r ;  d = nt*16 + c
// 256 blocks * 256 threads; thread owns 8 consecutive f (16B loads/chunk).
// ---------------------------------------------------------------------------
__global__ __launch_bounds__(256) void p1_reduce(const __bf16* __restrict__ ws1,
                                                 __bf16* __restrict__ ws2) {
    const int t   = blockIdx.x * 256 + threadIdx.x;  // 65536 threads
    const int bh  = t >> 11;
    const int r11 = t & 2047;

    const __bf16* base = ws1 + (size_t)bh * (DIM * DIM) + r11 * 8;
    float s[8] = {0.f, 0.f, 0.f, 0.f, 0.f, 0.f, 0.f, 0.f};
#pragma unroll
    for (int ch = 0; ch < CHUNKS; ++ch) {
        bf16x8 a = *(const bf16x8*)(base + (size_t)ch * BHN * DIM * DIM);
#pragma unroll
        for (int i = 0; i < 8; ++i) s[i] += (float)a[i];
    }

    __bf16* dst = ws2 + (size_t)bh * (DIM * DIM);
#pragma unroll
    for (int i = 0; i < 8; ++i) {
        const int f  = r11 * 8 + i;
        const int nt = f >> 11;
        const int wv = (f >> 8) & 7;
        const int gg = (f >> 6) & 3;
        const int cc = (f >> 2) & 15;
        const int r  = f & 3;
        const int e  = wv * 16 + gg * 4 + r;
        const int d  = nt * 16 + cc;
        dst[e * DIM + (((d >> 3) ^ (e & 15)) * 8) + (d & 7)] = (__bf16)s[i];
    }
}

// ---------------------------------------------------------------------------
// Phase 2 (flipped operands): out[s][e] = v[s][e] + sum_d q[s][d] * kv[d][e]
// Compute C[e][s] = mfma(A = kv_frag (M=e), B = q_frag (N=s)).
// Each lane holds 4 CONSECUTIVE e per fragment -> f32x4 epilogue.
// grid = 32 heads * 32 row-chunks = 1024 blocks, 512 threads (8 waves).
// UNCHANGED all session: at the copy ceiling (~193MB / ~30us real, v from
// L3) -- this is why fusion onto p1's 256-block grid was rejected.
// ---------------------------------------------------------------------------
__global__ __launch_bounds__(512) void p2_qkv(const float* __restrict__ qin,
                                              const float* __restrict__ vin,
                                              const __bf16* __restrict__ ws2,
                                              float* __restrict__ outp) {
    __shared__ __align__(16) __bf16 kvs[DIM * DIM];

    const int bh = blockIdx.x & 31;
    const int rc = blockIdx.x >> 5;
    const int tid = threadIdx.x;

    {   // linear 16B-copy of the (already swizzled) 32 KB head slab into LDS
        const uint4* src = (const uint4*)(ws2 + (size_t)bh * DIM * DIM);
        uint4* dst = (uint4*)kvs;
#pragma unroll
        for (int j = 0; j < 4; ++j) dst[tid + j * 512] = src[tid + j * 512];
    }
    __syncthreads();

    const int w = tid >> 6;
    const int l = tid & 63;
    const int g = l >> 4;
    const int c = l & 15;
    const int s = rc * 128 + w * 16 + c;     // this lane's output row

    // hoist all 4 Q fragments: B[d][s], lane holds q[s][ks*32 + g*8 .. +8)
    const float* qrow = qin + (size_t)bh * SEQ * DIM + (size_t)s * DIM + g * 8;
    bf16x8 bq[4];
#pragma unroll
    for (int ks = 0; ks < 4; ++ks) {
        f32x4 x = *(const f32x4*)(qrow + ks * 32);
        f32x4 y = *(const f32x4*)(qrow + ks * 32 + 4);
        float tmp[8];
        tmp[0]=x[0]; tmp[1]=x[1]; tmp[2]=x[2]; tmp[3]=x[3];
        tmp[4]=y[0]; tmp[5]=y[1]; tmp[6]=y[2]; tmp[7]=y[3];
        bq[ks] = cvt8(tmp);
    }

    f32x4 acc[8];
#pragma unroll
    for (int et = 0; et < 8; ++et) acc[et] = (f32x4){0.f, 0.f, 0.f, 0.f};

#pragma unroll
    for (int ks = 0; ks < 4; ++ks) {
#pragma unroll
        for (int et = 0; et < 8; ++et) {
            const int e = et * 16 + c;                 // A's M index = lane&15
            const int slot = (ks * 4 + g) ^ c;         // unswizzle: d-slice = ks*32+g*8
            bf16x8 a = *(const bf16x8*)&kvs[e * DIM + slot * 8];
            acc[et] = __builtin_amdgcn_mfma_f32_16x16x32_bf16(a, bq[ks], acc[et], 0, 0, 0);
        }
    }

    // epilogue: lane holds out[s][et*16 + g*4 .. +4) -> vectorized V add + store
    const float* vb = vin + (size_t)bh * SEQ * DIM;
    float* ob = outp + (size_t)bh * SEQ * DIM;
#pragma unroll
    for (int et = 0; et < 8; ++et) {
        const size_t idx = (size_t)s * DIM + et * 16 + g * 4;
        f32x4 vv = *(const f32x4*)(vb + idx);
        f32x4 o = acc[et] + vv;
        *(f32x4*)(ob + idx) = o;
    }
}

// ---------------------------------------------------------------------------
// Workspace: ws1 (8 x 1 MiB bf16 partials) + ws2 (1 MiB reduced kv) = 9 MiB.
// ---------------------------------------------------------------------------
extern "C" void kernel_launch(void* const* d_in, const int* in_sizes, int n_in,
                              void* d_out, int out_size, void* d_ws, size_t ws_size,
                              hipStream_t stream) {
    const float* q = (const float*)d_in[0];
    const float* k = (const float*)d_in[1];
    const float* v = (const float*)d_in[2];
    float* out = (float*)d_out;

    __bf16* ws1 = (__bf16*)d_ws;                                   // 8 MiB partials
    __bf16* ws2 = (__bf16*)((char*)d_ws + (size_t)CHUNKS * BHN * DIM * DIM * 2);

    p1_kv<<<BHN * CHUNKS, 512, 0, stream>>>(k, v, ws1);
    p1_reduce<<<(BHN * DIM * DIM / 8) / 256, 256, 0, stream>>>(ws1, ws2);
    p2_qkv<<<BHN * (SEQ / 128), 512, 0, stream>>>(q, v, ws2, out);
}